// Round 15
// baseline (228.706 us; speedup 1.0000x reference)
//
#include <hip/hip_runtime.h>
#include <hip/hip_bf16.h>

#define BB 16
#define TT 1024
#define SS 4096
#define CS 512
#define QS 512
#define PS 512
#define NROW (BB*TT)

typedef unsigned short ushort_t;
typedef unsigned int u32;
typedef short bf16x8 __attribute__((ext_vector_type(8)));
typedef float f32x4 __attribute__((ext_vector_type(4)));

#define AS1 __attribute__((address_space(1)))
#define AS3 __attribute__((address_space(3)))

__device__ __forceinline__ void gl2l16(const void* g, void* l) {
    __builtin_amdgcn_global_load_lds((const AS1 u32*)g, (AS3 u32*)l, 16, 0, 0);
}

__device__ __forceinline__ ushort_t f2bf(float f) {
    u32 x = __float_as_uint(f);
    return (ushort_t)((x + 0x7fffu + ((x >> 16) & 1u)) >> 16);
}
__device__ __forceinline__ float bf2f(ushort_t b) {
    return __uint_as_float(((u32)b) << 16);
}

// ---------------------------------------------------------------------------
// conv (fused): blocks 0..8191 -> A'; 8192..9215 -> Bt' + cnt; 9216..9231 ->
// zero hist/cur (4096 ints)
// ---------------------------------------------------------------------------
__global__ __launch_bounds__(256) void k_conv(const float* __restrict__ c,
                                              const float* __restrict__ Wa,
                                              const float* __restrict__ Wp,
                                              ushort_t* __restrict__ A,
                                              ushort_t* __restrict__ B,
                                              int* __restrict__ cnt,
                                              int* __restrict__ hist,
                                              int* __restrict__ cur) {
    const int blk = blockIdx.x;
    const int t = threadIdx.x;
    if (blk < 8192) {
        const int i = blk * 256 + t;
        const int m = i >> 7;
        const int k = (i & 127) * 4;
        float4 v = *(const float4*)(c + (size_t)m * CS + k);
        ushort4 hi, lo;
        hi.x = f2bf(v.x); lo.x = f2bf(v.x - bf2f(hi.x));
        hi.y = f2bf(v.y); lo.y = f2bf(v.y - bf2f(hi.y));
        hi.z = f2bf(v.z); lo.z = f2bf(v.z - bf2f(hi.z));
        hi.w = f2bf(v.w); lo.w = f2bf(v.w - bf2f(hi.w));
        *(ushort4*)(A + (size_t)m * 1024 + k)       = hi;
        *(ushort4*)(A + (size_t)m * 1024 + 512 + k) = lo;
    } else if (blk < 9216) {
        const int n = blk - 8192;
        if (n == 0 && t < 2) cnt[t] = 0;
        #pragma unroll
        for (int kk = 0; kk < 2; ++kk) {
            const int k = t + 256 * kk;
            float v = (n < 512) ? Wa[(size_t)k * QS + n] : Wp[(size_t)(n - 512) * CS + k];
            ushort_t hi = f2bf(v);
            ushort_t lo = f2bf(v - bf2f(hi));
            B[(size_t)n * 1024 + k]       = hi;
            B[(size_t)n * 1024 + 512 + k] = lo;
        }
    } else {
        const int idx = (blk - 9216) * 256 + t;   // 0..4095
        if (idx < 2048) hist[idx] = 0;
        else cur[idx - 2048] = 0;
    }
}

// ---------------------------------------------------------------------------
// GEMM (round-12 pair schedule, exact): C[16384 x 1024] = A' x Bt'^T.
// 256x256 tile, 16 waves, BK=64, 8-slot x 16KB LDS ring, 24 barriers.
// ---------------------------------------------------------------------------
__global__ __launch_bounds__(1024, 4) void k_gemm(const ushort_t* __restrict__ A,
                                                  const ushort_t* __restrict__ B,
                                                  const float* __restrict__ V_p,
                                                  float* __restrict__ u,
                                                  float* __restrict__ zpart) {
    __shared__ ushort_t lds[8][8192];   // 8 x 16 KB
    const int tid = threadIdx.x;
    const int l = tid & 63;
    const int w = tid >> 6;
    const int wm = w >> 2;
    const int wn = w & 3;
    const int ln = l & 15, lh = l >> 4;

    const int orig = blockIdx.x;
    const int swz = ((orig & 7) << 5) + (orig >> 3);
    const int m0 = (swz >> 2) * 256;
    const int nt = swz & 3;
    const int n0 = nt * 256;

    const int srow = tid >> 2;
    const int scg  = tid & 3;
    const int scol0 = (scg ^ ((srow >> 1) & 3)) * 8;

    const int swzr = (lh ^ ((ln >> 1) & 3)) << 3;
    int aoffL[4], boffL[4];
    #pragma unroll
    for (int mi = 0; mi < 4; ++mi)
        aoffL[mi] = (wm * 64 + mi * 16 + ln) * 32 + swzr;
    #pragma unroll
    for (int ni = 0; ni < 4; ++ni)
        boffL[ni] = (wn * 64 + ni * 16 + ln) * 32 + swzr;

    f32x4 acc[4][4];
    #pragma unroll
    for (int a = 0; a < 4; ++a)
        #pragma unroll
        for (int b2 = 0; b2 < 4; ++b2) acc[a][b2] = (f32x4){0.f, 0.f, 0.f, 0.f};

    auto STAGE = [&](int c) {
        const int tt = c >> 2, rem = c & 3, kh = rem >> 1;
        const int blk = tt >> 3, k0 = (tt & 7) << 6;
        const ushort_t* src;
        if (rem & 1) {
            const int boff = (blk == 1) ? 512 : 0;
            src = B + (size_t)(n0 + srow) * 1024 + boff + k0 + kh * 32 + scol0;
        } else {
            const int aoff = (blk == 2) ? 512 : 0;
            src = A + (size_t)(m0 + srow) * 1024 + aoff + k0 + kh * 32 + scol0;
        }
        gl2l16(src, &lds[c & 7][tid * 8]);
    };

    #pragma unroll
    for (int c = 0; c < 4; ++c) STAGE(c);
    asm volatile("s_waitcnt vmcnt(0)" ::: "memory");
    __builtin_amdgcn_s_barrier();

    #pragma unroll 1
    for (int t = 0; t < 24; ++t) {
        if (t < 23) {
            #pragma unroll
            for (int i = 0; i < 4; ++i) STAGE(4 * t + 4 + i);
        }
        {
            const ushort_t* bA = &lds[(4 * t) & 7][0];
            const ushort_t* bB = &lds[(4 * t + 1) & 7][0];
            bf16x8 af[4], bb[4];
            #pragma unroll
            for (int mi = 0; mi < 4; ++mi)
                af[mi] = *(const bf16x8*)(bA + aoffL[mi]);
            #pragma unroll
            for (int ni = 0; ni < 4; ++ni)
                bb[ni] = *(const bf16x8*)(bB + boffL[ni]);
            __builtin_amdgcn_s_setprio(1);
            #pragma unroll
            for (int mi = 0; mi < 4; ++mi)
                #pragma unroll
                for (int ni = 0; ni < 4; ++ni)
                    acc[mi][ni] = __builtin_amdgcn_mfma_f32_16x16x32_bf16(
                        af[mi], bb[ni], acc[mi][ni], 0, 0, 0);
            __builtin_amdgcn_s_setprio(0);
        }
        {
            const ushort_t* bA = &lds[(4 * t + 2) & 7][0];
            const ushort_t* bB = &lds[(4 * t + 3) & 7][0];
            bf16x8 af[4], bb[4];
            #pragma unroll
            for (int mi = 0; mi < 4; ++mi)
                af[mi] = *(const bf16x8*)(bA + aoffL[mi]);
            #pragma unroll
            for (int ni = 0; ni < 4; ++ni)
                bb[ni] = *(const bf16x8*)(bB + boffL[ni]);
            __builtin_amdgcn_s_setprio(1);
            #pragma unroll
            for (int mi = 0; mi < 4; ++mi)
                #pragma unroll
                for (int ni = 0; ni < 4; ++ni)
                    acc[mi][ni] = __builtin_amdgcn_mfma_f32_16x16x32_bf16(
                        af[mi], bb[ni], acc[mi][ni], 0, 0, 0);
            __builtin_amdgcn_s_setprio(0);
        }
        asm volatile("s_waitcnt vmcnt(0)" ::: "memory");
        __builtin_amdgcn_s_barrier();
    }

    if (nt < 2) {
        #pragma unroll
        for (int mi = 0; mi < 4; ++mi) {
            #pragma unroll
            for (int r = 0; r < 4; ++r) {
                const int m = m0 + wm * 64 + mi * 16 + lh * 4 + r;
                float* up = u + (size_t)m * QS + nt * 256 + wn * 64 + ln;
                #pragma unroll
                for (int ni = 0; ni < 4; ++ni) up[ni * 16] = acc[mi][ni][r];
            }
        }
    } else {
        float vp[4];
        #pragma unroll
        for (int ni = 0; ni < 4; ++ni)
            vp[ni] = V_p[(nt - 2) * 256 + wn * 64 + ni * 16 + ln];
        #pragma unroll
        for (int mi = 0; mi < 4; ++mi) {
            #pragma unroll
            for (int r = 0; r < 4; ++r) {
                float sv = 0.f;
                #pragma unroll
                for (int ni = 0; ni < 4; ++ni) sv += tanhf(acc[mi][ni][r]) * vp[ni];
                sv += __shfl_xor(sv, 1, 64);
                sv += __shfl_xor(sv, 2, 64);
                sv += __shfl_xor(sv, 4, 64);
                sv += __shfl_xor(sv, 8, 64);
                if (ln == 0)
                    zpart[(size_t)(m0 + wm * 64 + mi * 16 + lh * 4 + r) * 8 +
                          (nt - 2) * 4 + wn] = sv;
            }
        }
    }
}

// ---------------------------------------------------------------------------
// k_z: z = sum(zpart); p_t, trunc; append near-boundary rows to list1
// ---------------------------------------------------------------------------
__global__ __launch_bounds__(256) void k_z(const float* __restrict__ zpart,
                                           float* __restrict__ pt, int* __restrict__ tr,
                                           int* __restrict__ list1, int* __restrict__ cnt1) {
    const int row = blockIdx.x * 256 + threadIdx.x;
    const float4 a = *(const float4*)(zpart + (size_t)row * 8);
    const float4 b = *(const float4*)(zpart + (size_t)row * 8 + 4);
    float z = ((a.x + a.y) + (a.z + a.w)) + ((b.x + b.y) + (b.z + b.w));
    float ptv = 4096.f / (1.f + expf(-z));
    float fr = ptv - floorf(ptv);
    pt[row] = ptv;
    tr[row] = (int)ptv;
    if (fr < 0.06f || fr > 0.94f) {
        int i = atomicAdd(cnt1, 1);
        list1[i] = row;
    }
}

// ---------------------------------------------------------------------------
// rep1: batched f32 refine of p_t for listed rows; 8 rows per group.
// ---------------------------------------------------------------------------
__global__ __launch_bounds__(256) void k_rep1(
    const float* __restrict__ c_t, const float* __restrict__ W_p,
    const float* __restrict__ V_p, float* __restrict__ pt, int* __restrict__ tr,
    const int* __restrict__ list1, const int* __restrict__ cnt1,
    int* __restrict__ list2, int* __restrict__ cnt2)
{
    const int tid = threadIdx.x;
    const int lane = tid & 63;
    const int wid = tid >> 6;
    const int n1 = cnt1[0];
    __shared__ float cl[8][132 * 4];
    __shared__ double zl[4][8];
    __shared__ int rows_s[8];

    for (int g0 = blockIdx.x * 8; g0 < n1; g0 += gridDim.x * 8) {
        const int nr = min(8, n1 - g0);
        __syncthreads();
        if (tid < nr) rows_s[tid] = list1[g0 + tid];
        __syncthreads();
        for (int idx = tid; idx < nr * 128; idx += 256) {
            int r = idx >> 7, k = (idx & 127) * 4;
            *(float4*)&cl[r][k] = *(const float4*)(c_t + (size_t)rows_s[r] * CS + k);
        }
        __syncthreads();

        const float* wp0 = W_p + (size_t)tid * CS;
        const float* wp1 = W_p + (size_t)(tid + 256) * CS;
        f32x4 acc[2][8];
        #pragma unroll
        for (int p = 0; p < 2; ++p)
            #pragma unroll
            for (int r = 0; r < 8; ++r) acc[p][r] = (f32x4){0.f, 0.f, 0.f, 0.f};

        for (int k = 0; k < CS; k += 16) {
            f32x4 w0[4], w1[4];
            #pragma unroll
            for (int j = 0; j < 4; ++j) {
                w0[j] = *(const f32x4*)(wp0 + k + 4 * j);
                w1[j] = *(const f32x4*)(wp1 + k + 4 * j);
            }
            #pragma unroll
            for (int j = 0; j < 4; ++j) {
                #pragma unroll
                for (int r = 0; r < 8; ++r) {
                    f32x4 c4 = *(const f32x4*)&cl[r][k + 4 * j];
                    acc[0][r] += c4 * w0[j];
                    acc[1][r] += c4 * w1[j];
                }
            }
        }

        const float vp0 = V_p[tid];
        const float vp1 = V_p[tid + 256];
        double zp[8];
        #pragma unroll
        for (int r = 0; r < 8; ++r) {
            float X0 = (acc[0][r][0] + acc[0][r][1]) + (acc[0][r][2] + acc[0][r][3]);
            float X1 = (acc[1][r][0] + acc[1][r][1]) + (acc[1][r][2] + acc[1][r][3]);
            zp[r] = (double)(tanhf(X0) * vp0) + (double)(tanhf(X1) * vp1);
        }
        #pragma unroll
        for (int r = 0; r < 8; ++r) {
            double v = zp[r];
            #pragma unroll
            for (int o = 32; o > 0; o >>= 1) v += __shfl_down(v, o, 64);
            if (lane == 0) zl[wid][r] = v;
        }
        __syncthreads();
        if (tid < nr) {
            double z = (zl[0][tid] + zl[1][tid]) + (zl[2][tid] + zl[3][tid]);
            double ptv = 4096.0 / (1.0 + exp(-z));
            const int row = rows_s[tid];
            pt[row] = (float)ptv;
            tr[row] = (int)ptv;
            double fr = ptv - floor(ptv);
            if (fr < 5e-3 || fr > 0.995) {
                int i2 = atomicAdd(cnt2, 1);
                list2[i2] = row;
            }
        }
    }
}

// ---------------------------------------------------------------------------
// rep2a: full-f64 partials, work item i = (list idx)*8 + p-chunk(64).
// ---------------------------------------------------------------------------
__global__ __launch_bounds__(256) void k_rep2a(
    const float* __restrict__ c_t, const float* __restrict__ W_p,
    const float* __restrict__ V_p,
    const int* __restrict__ list2, const int* __restrict__ cnt2,
    double* __restrict__ zp2)
{
    const int tid = threadIdx.x;
    const int pl = tid & 63;
    const int kq = tid >> 6;
    const int n2 = cnt2[0];
    __shared__ float cl[CS];
    __shared__ double xsh[4][64];

    for (int i = blockIdx.x; i < n2 * 8; i += gridDim.x) {
        const int li = i >> 3;
        const int pc = i & 7;
        const int row = list2[li];
        const int p0 = pc * 64;
        __syncthreads();
        if (tid < 128)
            *(float4*)(cl + tid * 4) = *(const float4*)(c_t + (size_t)row * CS + tid * 4);
        __syncthreads();
        const float* wr = W_p + (size_t)(p0 + pl) * CS + kq * 128;
        const float* cr = cl + kq * 128;
        double Xa = 0.0, Xb = 0.0, Xc = 0.0, Xd = 0.0;
        #pragma unroll 4
        for (int k = 0; k < 128; k += 4) {
            float4 w4 = *(const float4*)(wr + k);
            float4 c4 = *(const float4*)(cr + k);
            Xa += (double)c4.x * w4.x;
            Xb += (double)c4.y * w4.y;
            Xc += (double)c4.z * w4.z;
            Xd += (double)c4.w * w4.w;
        }
        xsh[kq][pl] = (Xa + Xb) + (Xc + Xd);
        __syncthreads();
        if (tid < 64) {
            double X = (xsh[0][pl] + xsh[1][pl]) + (xsh[2][pl] + xsh[3][pl]);
            double zv = tanh(X) * (double)V_p[p0 + pl];
            #pragma unroll
            for (int o = 32; o > 0; o >>= 1) zv += __shfl_down(zv, o, 64);
            if (pl == 0) zp2[i] = zv;
        }
    }
}

// ---------------------------------------------------------------------------
// rep2b: per listed row, fixed-order sum of 8 partials -> sigmoid -> pt/tr
// ---------------------------------------------------------------------------
__global__ __launch_bounds__(256) void k_rep2b(
    const double* __restrict__ zp2, const int* __restrict__ list2,
    const int* __restrict__ cnt2, float* __restrict__ pt, int* __restrict__ tr)
{
    const int idx = blockIdx.x * 256 + threadIdx.x;
    if (idx >= cnt2[0]) return;
    const double* zr = zp2 + (size_t)idx * 8;
    double z = 0.0;
    #pragma unroll
    for (int j = 0; j < 8; ++j) z += zr[j];
    double ptv = 4096.0 / (1.0 + exp(-z));
    const int row = list2[idx];
    pt[row] = (float)ptv;
    tr[row] = (int)ptv;
}

// ---------------------------------------------------------------------------
// hist: bucket = b*128 + (tr>>5)  (2048 buckets, chunk = 32 s-values)
// ---------------------------------------------------------------------------
__global__ __launch_bounds__(256) void k_hist(const int* __restrict__ tr,
                                              int* __restrict__ hist) {
    const int row = blockIdx.x * 256 + threadIdx.x;
    const int bucket = ((row >> 10) << 7) + (tr[row] >> 5);
    atomicAdd(&hist[bucket], 1);
}

// ---------------------------------------------------------------------------
// scan: exclusive prefix over hist[2048] -> offA[2048]. 1 block, 1024 thr.
// ---------------------------------------------------------------------------
__global__ __launch_bounds__(1024) void k_scan(const int* __restrict__ hist,
                                               int* __restrict__ offA) {
    __shared__ int s0[1024], s1[1024];
    const int t = threadIdx.x;
    const int h0 = hist[2 * t];
    const int h1 = hist[2 * t + 1];
    s0[t] = h0 + h1;
    __syncthreads();
    int* src = s0;
    int* dst = s1;
    for (int off = 1; off < 1024; off <<= 1) {
        int v = src[t] + ((t >= off) ? src[t - off] : 0);
        dst[t] = v;
        __syncthreads();
        int* tmp = src; src = dst; dst = tmp;
    }
    const int excl = (t == 0) ? 0 : src[t - 1];
    offA[2 * t]     = excl;
    offA[2 * t + 1] = excl + h0;
}

// ---------------------------------------------------------------------------
// scatter: list[offA[bucket] + slot] = row (slot via atomic cursor)
// ---------------------------------------------------------------------------
__global__ __launch_bounds__(256) void k_scatter(const int* __restrict__ tr,
                                                 const int* __restrict__ offA,
                                                 int* __restrict__ cur,
                                                 int* __restrict__ list) {
    const int row = blockIdx.x * 256 + threadIdx.x;
    const int bucket = ((row >> 10) << 7) + (tr[row] >> 5);
    const int slot = atomicAdd(&cur[bucket], 1);
    list[offA[bucket] + slot] = row;
}

// ---------------------------------------------------------------------------
// attn_f: one block per bucket. Stage q[b][:, lo4..lo4+43] into LDS as
// tl[s_local][d] (44 x 513 floats, 90KB; consecutive-lane on both sides).
// Each wave handles one bt: lane owns d = l + 64j.
// ---------------------------------------------------------------------------
__global__ __launch_bounds__(1024) void k_attn_f(
    const float* __restrict__ q, const float* __restrict__ u,
    const float* __restrict__ pt, const int* __restrict__ tr,
    const int* __restrict__ hist, const int* __restrict__ offA,
    const int* __restrict__ list, float* __restrict__ out)
{
    const int bucket = blockIdx.x;
    const int n = hist[bucket];
    if (n == 0) return;
    const int b = bucket >> 7;
    const int c0 = (bucket & 127) << 5;
    const int lo4 = (c0 >= 4) ? ((c0 - 3) & ~3) : 0;

    __shared__ float tl[44 * 513];
    const int tid = threadIdx.x;
    const float* qb = q + (size_t)b * QS * SS;

    for (int idx = tid; idx < 512 * 11; idx += 1024) {
        const int d = idx & 511;
        const int c4 = idx >> 9;            // 0..10
        const int s = lo4 + c4 * 4;
        float4 v = make_float4(0.f, 0.f, 0.f, 0.f);
        if (s + 3 <= SS - 1)
            v = *(const float4*)(qb + (size_t)d * SS + s);
        tl[(c4 * 4 + 0) * 513 + d] = v.x;
        tl[(c4 * 4 + 1) * 513 + d] = v.y;
        tl[(c4 * 4 + 2) * 513 + d] = v.z;
        tl[(c4 * 4 + 3) * 513 + d] = v.w;
    }
    __syncthreads();

    const int wv = tid >> 6;
    const int l = tid & 63;
    const int base = offA[bucket];

    for (int wi = wv; wi < n; wi += 16) {
        const int bt = list[base + wi];
        const float ptv = pt[bt];
        const int tn = tr[bt];

        bool val[7];
        int pos[7];
        #pragma unroll
        for (int w = 0; w < 7; ++w) {
            int sv = tn + w - 2;
            sv = sv < 0 ? 0 : (sv > SS + 1 ? SS + 1 : sv);
            if (sv == SS + 1) sv = 0;
            val[w] = (sv != 0);
            pos[w] = sv - 1;
        }

        float uv[8];
        #pragma unroll
        for (int j = 0; j < 8; ++j)
            uv[j] = u[(size_t)bt * QS + l + 64 * j];

        float qg[7][8];
        #pragma unroll
        for (int w = 0; w < 7; ++w) {
            if (val[w]) {
                const float* tr0 = &tl[(pos[w] - lo4) * 513 + l];
                #pragma unroll
                for (int j = 0; j < 8; ++j) qg[w][j] = tr0[64 * j];
            } else {
                #pragma unroll
                for (int j = 0; j < 8; ++j) qg[w][j] = 0.f;
            }
        }

        float at[7];
        #pragma unroll
        for (int w = 0; w < 7; ++w) {
            float p = 0.f;
            #pragma unroll
            for (int j = 0; j < 8; ++j) p = fmaf(qg[w][j], uv[j], p);
            #pragma unroll
            for (int o = 1; o < 64; o <<= 1) p += __shfl_xor(p, o, 64);
            at[w] = p;
        }

        float m = -1e30f;
        #pragma unroll
        for (int w = 0; w < 7; ++w) if (val[w]) m = fmaxf(m, at[w]);
        float e[7], den = 0.f;
        #pragma unroll
        for (int w = 0; w < 7; ++w) { e[w] = val[w] ? expf(at[w] - m) : 0.f; den += e[w]; }
        const float inv = 1.f / den;

        float acc[8] = {0.f, 0.f, 0.f, 0.f, 0.f, 0.f, 0.f, 0.f};
        #pragma unroll
        for (int w = 0; w < 7; ++w) {
            if (val[w]) {
                float d = ((float)pos[w] - ptv) * (1.f / 3.f);
                float wt = e[w] * inv * expf(-2.f * d * d);
                #pragma unroll
                for (int j = 0; j < 8; ++j) acc[j] = fmaf(wt, qg[w][j], acc[j]);
            }
        }

        #pragma unroll
        for (int j = 0; j < 8; ++j)
            out[(size_t)bt * QS + l + 64 * j] = acc[j];
    }
}

// ---------------------------------------------------------------------------
extern "C" void kernel_launch(void* const* d_in, const int* in_sizes, int n_in,
                              void* d_out, int out_size, void* d_ws, size_t ws_size,
                              hipStream_t stream) {
    const float* q   = (const float*)d_in[0];
    const float* c_t = (const float*)d_in[1];
    const float* W_a = (const float*)d_in[2];
    const float* W_p = (const float*)d_in[3];
    const float* V_p = (const float*)d_in[4];
    float* out = (float*)d_out;

    char* ws = (char*)d_ws;
    ushort_t* Ap   = (ushort_t*)(ws);                      // 32 MB
    ushort_t* Bp   = (ushort_t*)(ws + 33554432);           // 2 MB
    float*    u    = (float*)  (ws + 35651584);            // 33.5 MB
    float*    zp   = (float*)  (ws + 69206016);            // 512 KB
    float*    pt   = (float*)  (ws + 69730304);            // 64 KB
    int*      tr   = (int*)    (ws + 69795840);            // 64 KB
    int*      l1   = (int*)    (ws + 69861376);            // 64 KB
    int*      l2   = (int*)    (ws + 69926912);            // 64 KB
    int*      cnt  = (int*)    (ws + 69992448);            // 8 B (pad 1KB)
    double*   zp2  = (double*) (ws + 69993472);            // 128 KB
    int*      hist = (int*)    (ws + 70124544);            // 8 KB
    int*      offA = (int*)    (ws + 70132736);            // 8 KB
    int*      cur  = (int*)    (ws + 70140928);            // 8 KB
    int*      list = (int*)    (ws + 70149120);            // 64 KB

    hipLaunchKernelGGL(k_conv, dim3(9232), dim3(256), 0, stream,
                       c_t, W_a, W_p, Ap, Bp, cnt, hist, cur);
    hipLaunchKernelGGL(k_gemm, dim3(256), dim3(1024), 0, stream, Ap, Bp, V_p, u, zp);
    hipLaunchKernelGGL(k_z, dim3(64), dim3(256), 0, stream, zp, pt, tr, l1, cnt);
    hipLaunchKernelGGL(k_rep1, dim3(512), dim3(256), 0, stream,
                       c_t, W_p, V_p, pt, tr, l1, cnt, l2, cnt + 1);
    hipLaunchKernelGGL(k_rep2a, dim3(512), dim3(256), 0, stream,
                       c_t, W_p, V_p, l2, cnt + 1, zp2);
    hipLaunchKernelGGL(k_rep2b, dim3(64), dim3(256), 0, stream,
                       zp2, l2, cnt + 1, pt, tr);
    hipLaunchKernelGGL(k_hist, dim3(64), dim3(256), 0, stream, tr, hist);
    hipLaunchKernelGGL(k_scan, dim3(1), dim3(1024), 0, stream, hist, offA);
    hipLaunchKernelGGL(k_scatter, dim3(64), dim3(256), 0, stream, tr, offA, cur, list);
    hipLaunchKernelGGL(k_attn_f, dim3(2048), dim3(1024), 0, stream,
                       q, u, pt, tr, hist, offA, list, out);
}

// Round 16
// 218.709 us; speedup vs baseline: 1.0457x; 1.0457x over previous
//
#include <hip/hip_runtime.h>
#include <hip/hip_bf16.h>

#define BB 16
#define TT 1024
#define SS 4096
#define CS 512
#define QS 512
#define PS 512
#define NROW (BB*TT)

typedef unsigned short ushort_t;
typedef unsigned int u32;
typedef short bf16x8 __attribute__((ext_vector_type(8)));
typedef float f32x4 __attribute__((ext_vector_type(4)));

#define AS1 __attribute__((address_space(1)))
#define AS3 __attribute__((address_space(3)))

__device__ __forceinline__ void gl2l16(const void* g, void* l) {
    __builtin_amdgcn_global_load_lds((const AS1 u32*)g, (AS3 u32*)l, 16, 0, 0);
}

__device__ __forceinline__ ushort_t f2bf(float f) {
    u32 x = __float_as_uint(f);
    return (ushort_t)((x + 0x7fffu + ((x >> 16) & 1u)) >> 16);
}
__device__ __forceinline__ float bf2f(ushort_t b) {
    return __uint_as_float(((u32)b) << 16);
}

// ---------------------------------------------------------------------------
// conv (fused): blocks 0..8191 -> A'; 8192..9215 -> Bt' + cnt; 9216..9231 ->
// zero hist/cur (4096 ints)
// ---------------------------------------------------------------------------
__global__ __launch_bounds__(256) void k_conv(const float* __restrict__ c,
                                              const float* __restrict__ Wa,
                                              const float* __restrict__ Wp,
                                              ushort_t* __restrict__ A,
                                              ushort_t* __restrict__ B,
                                              int* __restrict__ cnt,
                                              int* __restrict__ hist,
                                              int* __restrict__ cur) {
    const int blk = blockIdx.x;
    const int t = threadIdx.x;
    if (blk < 8192) {
        const int i = blk * 256 + t;
        const int m = i >> 7;
        const int k = (i & 127) * 4;
        float4 v = *(const float4*)(c + (size_t)m * CS + k);
        ushort4 hi, lo;
        hi.x = f2bf(v.x); lo.x = f2bf(v.x - bf2f(hi.x));
        hi.y = f2bf(v.y); lo.y = f2bf(v.y - bf2f(hi.y));
        hi.z = f2bf(v.z); lo.z = f2bf(v.z - bf2f(hi.z));
        hi.w = f2bf(v.w); lo.w = f2bf(v.w - bf2f(hi.w));
        *(ushort4*)(A + (size_t)m * 1024 + k)       = hi;
        *(ushort4*)(A + (size_t)m * 1024 + 512 + k) = lo;
    } else if (blk < 9216) {
        const int n = blk - 8192;
        if (n == 0 && t < 2) cnt[t] = 0;
        #pragma unroll
        for (int kk = 0; kk < 2; ++kk) {
            const int k = t + 256 * kk;
            float v = (n < 512) ? Wa[(size_t)k * QS + n] : Wp[(size_t)(n - 512) * CS + k];
            ushort_t hi = f2bf(v);
            ushort_t lo = f2bf(v - bf2f(hi));
            B[(size_t)n * 1024 + k]       = hi;
            B[(size_t)n * 1024 + 512 + k] = lo;
        }
    } else {
        const int idx = (blk - 9216) * 256 + t;   // 0..4095
        if (idx < 2048) hist[idx] = 0;
        else cur[idx - 2048] = 0;
    }
}

// ---------------------------------------------------------------------------
// GEMM (round-12 pair schedule, exact): C[16384 x 1024] = A' x Bt'^T.
// 256x256 tile, 16 waves, BK=64, 8-slot x 16KB LDS ring, 24 barriers.
// ---------------------------------------------------------------------------
__global__ __launch_bounds__(1024, 4) void k_gemm(const ushort_t* __restrict__ A,
                                                  const ushort_t* __restrict__ B,
                                                  const float* __restrict__ V_p,
                                                  float* __restrict__ u,
                                                  float* __restrict__ zpart) {
    __shared__ ushort_t lds[8][8192];   // 8 x 16 KB
    const int tid = threadIdx.x;
    const int l = tid & 63;
    const int w = tid >> 6;
    const int wm = w >> 2;
    const int wn = w & 3;
    const int ln = l & 15, lh = l >> 4;

    const int orig = blockIdx.x;
    const int swz = ((orig & 7) << 5) + (orig >> 3);
    const int m0 = (swz >> 2) * 256;
    const int nt = swz & 3;
    const int n0 = nt * 256;

    const int srow = tid >> 2;
    const int scg  = tid & 3;
    const int scol0 = (scg ^ ((srow >> 1) & 3)) * 8;

    const int swzr = (lh ^ ((ln >> 1) & 3)) << 3;
    int aoffL[4], boffL[4];
    #pragma unroll
    for (int mi = 0; mi < 4; ++mi)
        aoffL[mi] = (wm * 64 + mi * 16 + ln) * 32 + swzr;
    #pragma unroll
    for (int ni = 0; ni < 4; ++ni)
        boffL[ni] = (wn * 64 + ni * 16 + ln) * 32 + swzr;

    f32x4 acc[4][4];
    #pragma unroll
    for (int a = 0; a < 4; ++a)
        #pragma unroll
        for (int b2 = 0; b2 < 4; ++b2) acc[a][b2] = (f32x4){0.f, 0.f, 0.f, 0.f};

    auto STAGE = [&](int c) {
        const int tt = c >> 2, rem = c & 3, kh = rem >> 1;
        const int blk = tt >> 3, k0 = (tt & 7) << 6;
        const ushort_t* src;
        if (rem & 1) {
            const int boff = (blk == 1) ? 512 : 0;
            src = B + (size_t)(n0 + srow) * 1024 + boff + k0 + kh * 32 + scol0;
        } else {
            const int aoff = (blk == 2) ? 512 : 0;
            src = A + (size_t)(m0 + srow) * 1024 + aoff + k0 + kh * 32 + scol0;
        }
        gl2l16(src, &lds[c & 7][tid * 8]);
    };

    #pragma unroll
    for (int c = 0; c < 4; ++c) STAGE(c);
    asm volatile("s_waitcnt vmcnt(0)" ::: "memory");
    __builtin_amdgcn_s_barrier();

    #pragma unroll 1
    for (int t = 0; t < 24; ++t) {
        if (t < 23) {
            #pragma unroll
            for (int i = 0; i < 4; ++i) STAGE(4 * t + 4 + i);
        }
        {
            const ushort_t* bA = &lds[(4 * t) & 7][0];
            const ushort_t* bB = &lds[(4 * t + 1) & 7][0];
            bf16x8 af[4], bb[4];
            #pragma unroll
            for (int mi = 0; mi < 4; ++mi)
                af[mi] = *(const bf16x8*)(bA + aoffL[mi]);
            #pragma unroll
            for (int ni = 0; ni < 4; ++ni)
                bb[ni] = *(const bf16x8*)(bB + boffL[ni]);
            __builtin_amdgcn_s_setprio(1);
            #pragma unroll
            for (int mi = 0; mi < 4; ++mi)
                #pragma unroll
                for (int ni = 0; ni < 4; ++ni)
                    acc[mi][ni] = __builtin_amdgcn_mfma_f32_16x16x32_bf16(
                        af[mi], bb[ni], acc[mi][ni], 0, 0, 0);
            __builtin_amdgcn_s_setprio(0);
        }
        {
            const ushort_t* bA = &lds[(4 * t + 2) & 7][0];
            const ushort_t* bB = &lds[(4 * t + 3) & 7][0];
            bf16x8 af[4], bb[4];
            #pragma unroll
            for (int mi = 0; mi < 4; ++mi)
                af[mi] = *(const bf16x8*)(bA + aoffL[mi]);
            #pragma unroll
            for (int ni = 0; ni < 4; ++ni)
                bb[ni] = *(const bf16x8*)(bB + boffL[ni]);
            __builtin_amdgcn_s_setprio(1);
            #pragma unroll
            for (int mi = 0; mi < 4; ++mi)
                #pragma unroll
                for (int ni = 0; ni < 4; ++ni)
                    acc[mi][ni] = __builtin_amdgcn_mfma_f32_16x16x32_bf16(
                        af[mi], bb[ni], acc[mi][ni], 0, 0, 0);
            __builtin_amdgcn_s_setprio(0);
        }
        asm volatile("s_waitcnt vmcnt(0)" ::: "memory");
        __builtin_amdgcn_s_barrier();
    }

    if (nt < 2) {
        #pragma unroll
        for (int mi = 0; mi < 4; ++mi) {
            #pragma unroll
            for (int r = 0; r < 4; ++r) {
                const int m = m0 + wm * 64 + mi * 16 + lh * 4 + r;
                float* up = u + (size_t)m * QS + nt * 256 + wn * 64 + ln;
                #pragma unroll
                for (int ni = 0; ni < 4; ++ni) up[ni * 16] = acc[mi][ni][r];
            }
        }
    } else {
        float vp[4];
        #pragma unroll
        for (int ni = 0; ni < 4; ++ni)
            vp[ni] = V_p[(nt - 2) * 256 + wn * 64 + ni * 16 + ln];
        #pragma unroll
        for (int mi = 0; mi < 4; ++mi) {
            #pragma unroll
            for (int r = 0; r < 4; ++r) {
                float sv = 0.f;
                #pragma unroll
                for (int ni = 0; ni < 4; ++ni) sv += tanhf(acc[mi][ni][r]) * vp[ni];
                sv += __shfl_xor(sv, 1, 64);
                sv += __shfl_xor(sv, 2, 64);
                sv += __shfl_xor(sv, 4, 64);
                sv += __shfl_xor(sv, 8, 64);
                if (ln == 0)
                    zpart[(size_t)(m0 + wm * 64 + mi * 16 + lh * 4 + r) * 8 +
                          (nt - 2) * 4 + wn] = sv;
            }
        }
    }
}

// ---------------------------------------------------------------------------
// k_z: z = sum(zpart); p_t, trunc; append near-boundary rows to list1
// ---------------------------------------------------------------------------
__global__ __launch_bounds__(256) void k_z(const float* __restrict__ zpart,
                                           float* __restrict__ pt, int* __restrict__ tr,
                                           int* __restrict__ list1, int* __restrict__ cnt1) {
    const int row = blockIdx.x * 256 + threadIdx.x;
    const float4 a = *(const float4*)(zpart + (size_t)row * 8);
    const float4 b = *(const float4*)(zpart + (size_t)row * 8 + 4);
    float z = ((a.x + a.y) + (a.z + a.w)) + ((b.x + b.y) + (b.z + b.w));
    float ptv = 4096.f / (1.f + expf(-z));
    float fr = ptv - floorf(ptv);
    pt[row] = ptv;
    tr[row] = (int)ptv;
    if (fr < 0.06f || fr > 0.94f) {
        int i = atomicAdd(cnt1, 1);
        list1[i] = row;
    }
}

// ---------------------------------------------------------------------------
// rep1: batched f32 refine of p_t for listed rows; 8 rows per group.
// ---------------------------------------------------------------------------
__global__ __launch_bounds__(256) void k_rep1(
    const float* __restrict__ c_t, const float* __restrict__ W_p,
    const float* __restrict__ V_p, float* __restrict__ pt, int* __restrict__ tr,
    const int* __restrict__ list1, const int* __restrict__ cnt1,
    int* __restrict__ list2, int* __restrict__ cnt2)
{
    const int tid = threadIdx.x;
    const int lane = tid & 63;
    const int wid = tid >> 6;
    const int n1 = cnt1[0];
    __shared__ float cl[8][132 * 4];
    __shared__ double zl[4][8];
    __shared__ int rows_s[8];

    for (int g0 = blockIdx.x * 8; g0 < n1; g0 += gridDim.x * 8) {
        const int nr = min(8, n1 - g0);
        __syncthreads();
        if (tid < nr) rows_s[tid] = list1[g0 + tid];
        __syncthreads();
        for (int idx = tid; idx < nr * 128; idx += 256) {
            int r = idx >> 7, k = (idx & 127) * 4;
            *(float4*)&cl[r][k] = *(const float4*)(c_t + (size_t)rows_s[r] * CS + k);
        }
        __syncthreads();

        const float* wp0 = W_p + (size_t)tid * CS;
        const float* wp1 = W_p + (size_t)(tid + 256) * CS;
        f32x4 acc[2][8];
        #pragma unroll
        for (int p = 0; p < 2; ++p)
            #pragma unroll
            for (int r = 0; r < 8; ++r) acc[p][r] = (f32x4){0.f, 0.f, 0.f, 0.f};

        for (int k = 0; k < CS; k += 16) {
            f32x4 w0[4], w1[4];
            #pragma unroll
            for (int j = 0; j < 4; ++j) {
                w0[j] = *(const f32x4*)(wp0 + k + 4 * j);
                w1[j] = *(const f32x4*)(wp1 + k + 4 * j);
            }
            #pragma unroll
            for (int j = 0; j < 4; ++j) {
                #pragma unroll
                for (int r = 0; r < 8; ++r) {
                    f32x4 c4 = *(const f32x4*)&cl[r][k + 4 * j];
                    acc[0][r] += c4 * w0[j];
                    acc[1][r] += c4 * w1[j];
                }
            }
        }

        const float vp0 = V_p[tid];
        const float vp1 = V_p[tid + 256];
        double zp[8];
        #pragma unroll
        for (int r = 0; r < 8; ++r) {
            float X0 = (acc[0][r][0] + acc[0][r][1]) + (acc[0][r][2] + acc[0][r][3]);
            float X1 = (acc[1][r][0] + acc[1][r][1]) + (acc[1][r][2] + acc[1][r][3]);
            zp[r] = (double)(tanhf(X0) * vp0) + (double)(tanhf(X1) * vp1);
        }
        #pragma unroll
        for (int r = 0; r < 8; ++r) {
            double v = zp[r];
            #pragma unroll
            for (int o = 32; o > 0; o >>= 1) v += __shfl_down(v, o, 64);
            if (lane == 0) zl[wid][r] = v;
        }
        __syncthreads();
        if (tid < nr) {
            double z = (zl[0][tid] + zl[1][tid]) + (zl[2][tid] + zl[3][tid]);
            double ptv = 4096.0 / (1.0 + exp(-z));
            const int row = rows_s[tid];
            pt[row] = (float)ptv;
            tr[row] = (int)ptv;
            double fr = ptv - floor(ptv);
            if (fr < 5e-3 || fr > 0.995) {
                int i2 = atomicAdd(cnt2, 1);
                list2[i2] = row;
            }
        }
    }
}

// ---------------------------------------------------------------------------
// rep2a: full-f64 partials, work item i = (list idx)*8 + p-chunk(64).
// ---------------------------------------------------------------------------
__global__ __launch_bounds__(256) void k_rep2a(
    const float* __restrict__ c_t, const float* __restrict__ W_p,
    const float* __restrict__ V_p,
    const int* __restrict__ list2, const int* __restrict__ cnt2,
    double* __restrict__ zp2)
{
    const int tid = threadIdx.x;
    const int pl = tid & 63;
    const int kq = tid >> 6;
    const int n2 = cnt2[0];
    __shared__ float cl[CS];
    __shared__ double xsh[4][64];

    for (int i = blockIdx.x; i < n2 * 8; i += gridDim.x) {
        const int li = i >> 3;
        const int pc = i & 7;
        const int row = list2[li];
        const int p0 = pc * 64;
        __syncthreads();
        if (tid < 128)
            *(float4*)(cl + tid * 4) = *(const float4*)(c_t + (size_t)row * CS + tid * 4);
        __syncthreads();
        const float* wr = W_p + (size_t)(p0 + pl) * CS + kq * 128;
        const float* cr = cl + kq * 128;
        double Xa = 0.0, Xb = 0.0, Xc = 0.0, Xd = 0.0;
        #pragma unroll 4
        for (int k = 0; k < 128; k += 4) {
            float4 w4 = *(const float4*)(wr + k);
            float4 c4 = *(const float4*)(cr + k);
            Xa += (double)c4.x * w4.x;
            Xb += (double)c4.y * w4.y;
            Xc += (double)c4.z * w4.z;
            Xd += (double)c4.w * w4.w;
        }
        xsh[kq][pl] = (Xa + Xb) + (Xc + Xd);
        __syncthreads();
        if (tid < 64) {
            double X = (xsh[0][pl] + xsh[1][pl]) + (xsh[2][pl] + xsh[3][pl]);
            double zv = tanh(X) * (double)V_p[p0 + pl];
            #pragma unroll
            for (int o = 32; o > 0; o >>= 1) zv += __shfl_down(zv, o, 64);
            if (pl == 0) zp2[i] = zv;
        }
    }
}

// ---------------------------------------------------------------------------
// rep2b: per listed row, fixed-order sum of 8 partials -> sigmoid -> pt/tr
// ---------------------------------------------------------------------------
__global__ __launch_bounds__(256) void k_rep2b(
    const double* __restrict__ zp2, const int* __restrict__ list2,
    const int* __restrict__ cnt2, float* __restrict__ pt, int* __restrict__ tr)
{
    const int idx = blockIdx.x * 256 + threadIdx.x;
    if (idx >= cnt2[0]) return;
    const double* zr = zp2 + (size_t)idx * 8;
    double z = 0.0;
    #pragma unroll
    for (int j = 0; j < 8; ++j) z += zr[j];
    double ptv = 4096.0 / (1.0 + exp(-z));
    const int row = list2[idx];
    pt[row] = (float)ptv;
    tr[row] = (int)ptv;
}

// ---------------------------------------------------------------------------
// hist: bucket = b*128 + (tr>>5)  (2048 buckets, chunk = 32 s-values)
// ---------------------------------------------------------------------------
__global__ __launch_bounds__(256) void k_hist(const int* __restrict__ tr,
                                              int* __restrict__ hist) {
    const int row = blockIdx.x * 256 + threadIdx.x;
    const int bucket = ((row >> 10) << 7) + (tr[row] >> 5);
    atomicAdd(&hist[bucket], 1);
}

// ---------------------------------------------------------------------------
// scan: exclusive prefix over hist[2048] -> offA[2048]. 1 block, 1024 thr.
// ---------------------------------------------------------------------------
__global__ __launch_bounds__(1024) void k_scan(const int* __restrict__ hist,
                                               int* __restrict__ offA) {
    __shared__ int s0[1024], s1[1024];
    const int t = threadIdx.x;
    const int h0 = hist[2 * t];
    const int h1 = hist[2 * t + 1];
    s0[t] = h0 + h1;
    __syncthreads();
    int* src = s0;
    int* dst = s1;
    for (int off = 1; off < 1024; off <<= 1) {
        int v = src[t] + ((t >= off) ? src[t - off] : 0);
        dst[t] = v;
        __syncthreads();
        int* tmp = src; src = dst; dst = tmp;
    }
    const int excl = (t == 0) ? 0 : src[t - 1];
    offA[2 * t]     = excl;
    offA[2 * t + 1] = excl + h0;
}

// ---------------------------------------------------------------------------
// scatter: list[offA[bucket] + slot] = row (slot via atomic cursor)
// ---------------------------------------------------------------------------
__global__ __launch_bounds__(256) void k_scatter(const int* __restrict__ tr,
                                                 const int* __restrict__ offA,
                                                 int* __restrict__ cur,
                                                 int* __restrict__ list) {
    const int row = blockIdx.x * 256 + threadIdx.x;
    const int bucket = ((row >> 10) << 7) + (tr[row] >> 5);
    const int slot = atomicAdd(&cur[bucket], 1);
    list[offA[bucket] + slot] = row;
}

// ---------------------------------------------------------------------------
// attn_f: one block per bucket. Stage q[b][:, lo4..lo4+47] into LDS as
// tl[s_local][d] (48 x 513 floats, 98.4KB). COALESCED staging: c4-inner
// lane mapping -> consecutive lanes read contiguous 16B of the same q-row
// (12 lanes = 192B contiguous; ~16 CLs/wave-instr instead of 64).
// Read/compute path identical to round 15. Each wave handles one bt.
// ---------------------------------------------------------------------------
__global__ __launch_bounds__(1024) void k_attn_f(
    const float* __restrict__ q, const float* __restrict__ u,
    const float* __restrict__ pt, const int* __restrict__ tr,
    const int* __restrict__ hist, const int* __restrict__ offA,
    const int* __restrict__ list, float* __restrict__ out)
{
    const int bucket = blockIdx.x;
    const int n = hist[bucket];
    if (n == 0) return;
    const int b = bucket >> 7;
    const int c0 = (bucket & 127) << 5;
    const int lo4 = (c0 >= 4) ? ((c0 - 3) & ~3) : 0;

    __shared__ float tl[48 * 513];
    const int tid = threadIdx.x;
    const float* qb = q + (size_t)b * QS * SS;

    // coalesced staging: idx -> (d = idx/12, c4 = idx%12); 6 iters exactly
    for (int idx = tid; idx < 512 * 12; idx += 1024) {
        const int d = idx / 12;
        const int c4 = idx - d * 12;        // 0..11
        const int s = lo4 + c4 * 4;
        float4 v = make_float4(0.f, 0.f, 0.f, 0.f);
        if (s + 3 <= SS - 1)
            v = *(const float4*)(qb + (size_t)d * SS + s);
        tl[(c4 * 4 + 0) * 513 + d] = v.x;
        tl[(c4 * 4 + 1) * 513 + d] = v.y;
        tl[(c4 * 4 + 2) * 513 + d] = v.z;
        tl[(c4 * 4 + 3) * 513 + d] = v.w;
    }
    __syncthreads();

    const int wv = tid >> 6;
    const int l = tid & 63;
    const int base = offA[bucket];

    for (int wi = wv; wi < n; wi += 16) {
        const int bt = list[base + wi];
        const float ptv = pt[bt];
        const int tn = tr[bt];

        bool val[7];
        int pos[7];
        #pragma unroll
        for (int w = 0; w < 7; ++w) {
            int sv = tn + w - 2;
            sv = sv < 0 ? 0 : (sv > SS + 1 ? SS + 1 : sv);
            if (sv == SS + 1) sv = 0;
            val[w] = (sv != 0);
            pos[w] = sv - 1;
        }

        float uv[8];
        #pragma unroll
        for (int j = 0; j < 8; ++j)
            uv[j] = u[(size_t)bt * QS + l + 64 * j];

        float qg[7][8];
        #pragma unroll
        for (int w = 0; w < 7; ++w) {
            if (val[w]) {
                const float* tr0 = &tl[(pos[w] - lo4) * 513 + l];
                #pragma unroll
                for (int j = 0; j < 8; ++j) qg[w][j] = tr0[64 * j];
            } else {
                #pragma unroll
                for (int j = 0; j < 8; ++j) qg[w][j] = 0.f;
            }
        }

        float at[7];
        #pragma unroll
        for (int w = 0; w < 7; ++w) {
            float p = 0.f;
            #pragma unroll
            for (int j = 0; j < 8; ++j) p = fmaf(qg[w][j], uv[j], p);
            #pragma unroll
            for (int o = 1; o < 64; o <<= 1) p += __shfl_xor(p, o, 64);
            at[w] = p;
        }

        float m = -1e30f;
        #pragma unroll
        for (int w = 0; w < 7; ++w) if (val[w]) m = fmaxf(m, at[w]);
        float e[7], den = 0.f;
        #pragma unroll
        for (int w = 0; w < 7; ++w) { e[w] = val[w] ? expf(at[w] - m) : 0.f; den += e[w]; }
        const float inv = 1.f / den;

        float acc[8] = {0.f, 0.f, 0.f, 0.f, 0.f, 0.f, 0.f, 0.f};
        #pragma unroll
        for (int w = 0; w < 7; ++w) {
            if (val[w]) {
                float d = ((float)pos[w] - ptv) * (1.f / 3.f);
                float wt = e[w] * inv * expf(-2.f * d * d);
                #pragma unroll
                for (int j = 0; j < 8; ++j) acc[j] = fmaf(wt, qg[w][j], acc[j]);
            }
        }

        #pragma unroll
        for (int j = 0; j < 8; ++j)
            out[(size_t)bt * QS + l + 64 * j] = acc[j];
    }
}

// ---------------------------------------------------------------------------
extern "C" void kernel_launch(void* const* d_in, const int* in_sizes, int n_in,
                              void* d_out, int out_size, void* d_ws, size_t ws_size,
                              hipStream_t stream) {
    const float* q   = (const float*)d_in[0];
    const float* c_t = (const float*)d_in[1];
    const float* W_a = (const float*)d_in[2];
    const float* W_p = (const float*)d_in[3];
    const float* V_p = (const float*)d_in[4];
    float* out = (float*)d_out;

    char* ws = (char*)d_ws;
    ushort_t* Ap   = (ushort_t*)(ws);                      // 32 MB
    ushort_t* Bp   = (ushort_t*)(ws + 33554432);           // 2 MB
    float*    u    = (float*)  (ws + 35651584);            // 33.5 MB
    float*    zp   = (float*)  (ws + 69206016);            // 512 KB
    float*    pt   = (float*)  (ws + 69730304);            // 64 KB
    int*      tr   = (int*)    (ws + 69795840);            // 64 KB
    int*      l1   = (int*)    (ws + 69861376);            // 64 KB
    int*      l2   = (int*)    (ws + 69926912);            // 64 KB
    int*      cnt  = (int*)    (ws + 69992448);            // 8 B (pad 1KB)
    double*   zp2  = (double*) (ws + 69993472);            // 128 KB
    int*      hist = (int*)    (ws + 70124544);            // 8 KB
    int*      offA = (int*)    (ws + 70132736);            // 8 KB
    int*      cur  = (int*)    (ws + 70140928);            // 8 KB
    int*      list = (int*)    (ws + 70149120);            // 64 KB

    hipLaunchKernelGGL(k_conv, dim3(9232), dim3(256), 0, stream,
                       c_t, W_a, W_p, Ap, Bp, cnt, hist, cur);
    hipLaunchKernelGGL(k_gemm, dim3(256), dim3(1024), 0, stream, Ap, Bp, V_p, u, zp);
    hipLaunchKernelGGL(k_z, dim3(64), dim3(256), 0, stream, zp, pt, tr, l1, cnt);
    hipLaunchKernelGGL(k_rep1, dim3(512), dim3(256), 0, stream,
                       c_t, W_p, V_p, pt, tr, l1, cnt, l2, cnt + 1);
    hipLaunchKernelGGL(k_rep2a, dim3(512), dim3(256), 0, stream,
                       c_t, W_p, V_p, l2, cnt + 1, zp2);
    hipLaunchKernelGGL(k_rep2b, dim3(64), dim3(256), 0, stream,
                       zp2, l2, cnt + 1, pt, tr);
    hipLaunchKernelGGL(k_hist, dim3(64), dim3(256), 0, stream, tr, hist);
    hipLaunchKernelGGL(k_scan, dim3(1), dim3(1024), 0, stream, hist, offA);
    hipLaunchKernelGGL(k_scatter, dim3(64), dim3(256), 0, stream, tr, offA, cur, list);
    hipLaunchKernelGGL(k_attn_f, dim3(2048), dim3(1024), 0, stream,
                       q, u, pt, tr, hist, offA, list, out);
}